// Round 1
// baseline (701.791 us; speedup 1.0000x reference)
//
#include <hip/hip_runtime.h>
#include <hip/hip_bf16.h>
#include <math.h>

#define BDIM 32
#define TDIM 1025
#define DDIM 768
#define GRIDW 32
#define TPATCH 1024
#define SCALE 8.0f
#define EPSLN 1e-5f

// ---------------------------------------------------------------------------
// Kernel 1: fused QKV projection + LayerNorm(q,k) + alpha/sigma head.
// Each block: 64 rows of x (row = b*1025+t), all 192 output cols (q|k|v).
// Thread (ty,tx): rows ty*4+i, cols tx+16*j (j=0..3 q, 4..7 k, 8..11 v).
// ---------------------------------------------------------------------------
__global__ __launch_bounds__(256) void qkv_kernel(
    const float* __restrict__ x,
    const float* __restrict__ Wq, const float* __restrict__ Wk, const float* __restrict__ Wv,
    const float* __restrict__ gq, const float* __restrict__ bq,
    const float* __restrict__ gk, const float* __restrict__ bk,
    const float* __restrict__ Wsig, const float* __restrict__ bsig,
    const float* __restrict__ Wa, const float* __restrict__ ba,
    float* __restrict__ qo, float* __restrict__ ko, float* __restrict__ vo,
    float* __restrict__ a8, float* __restrict__ isx, float* __restrict__ isy)
{
    const int KT = 32;
    __shared__ float xs[64][36];    // pad 36: 16B-aligned float4, rows on distinct banks
    __shared__ float wt[192][36];   // W transposed: wt[c][kk]
    const int t  = threadIdx.x;
    const int ty = t >> 4, tx = t & 15;
    const int r0 = blockIdx.x * 64;
    const int NROW = BDIM * TDIM;

    float acc[4][12];
#pragma unroll
    for (int i = 0; i < 4; ++i)
#pragma unroll
        for (int j = 0; j < 12; ++j) acc[i][j] = 0.f;

    for (int k0 = 0; k0 < DDIM; k0 += KT) {
        __syncthreads();
        // stage x tile (64 x 32)
        for (int idx = t; idx < 64 * KT; idx += 256) {
            int rr = idx >> 5, kk = idx & 31;
            int row = r0 + rr;
            xs[rr][kk] = (row < NROW) ? x[(size_t)row * DDIM + k0 + kk] : 0.f;
        }
        // stage W tile transposed (192 cols x 32 k): coalesced over c
        for (int idx = t; idx < 192 * KT; idx += 256) {
            int kk = idx / 192, c = idx - kk * 192;
            float w;
            if (c < 64)       w = Wq[(k0 + kk) * 64 + c];
            else if (c < 128) w = Wk[(k0 + kk) * 64 + (c - 64)];
            else              w = Wv[(k0 + kk) * 64 + (c - 128)];
            wt[c][kk] = w;
        }
        __syncthreads();
#pragma unroll
        for (int kk4 = 0; kk4 < KT; kk4 += 4) {
            float4 xv[4];
#pragma unroll
            for (int i = 0; i < 4; ++i)
                xv[i] = *(const float4*)&xs[ty * 4 + i][kk4];
#pragma unroll
            for (int j = 0; j < 12; ++j) {
                float4 wv = *(const float4*)&wt[tx + 16 * j][kk4];
#pragma unroll
                for (int i = 0; i < 4; ++i) {
                    acc[i][j] += xv[i].x * wv.x;
                    acc[i][j] += xv[i].y * wv.y;
                    acc[i][j] += xv[i].z * wv.z;
                    acc[i][j] += xv[i].w * wv.w;
                }
            }
        }
    }

    // LayerNorm (q,k) + alpha/sigma head + writes
#pragma unroll
    for (int i = 0; i < 4; ++i) {
        const int row = r0 + ty * 4 + i;

        // ---- q LN ----
        float s1 = 0.f, s2 = 0.f;
#pragma unroll
        for (int j = 0; j < 4; ++j) { float a = acc[i][j]; s1 += a; s2 += a * a; }
#pragma unroll
        for (int off = 1; off < 16; off <<= 1) { s1 += __shfl_xor(s1, off); s2 += __shfl_xor(s2, off); }
        float mean = s1 * (1.f / 64.f);
        float var  = s2 * (1.f / 64.f) - mean * mean;
        float rstd = rsqrtf(var + EPSLN);
        float qn[4];
#pragma unroll
        for (int j = 0; j < 4; ++j) {
            int c = tx + 16 * j;
            qn[j] = (acc[i][j] - mean) * rstd * gq[c] + bq[c];
        }

        // ---- k LN ----
        s1 = 0.f; s2 = 0.f;
#pragma unroll
        for (int j = 0; j < 4; ++j) { float a = acc[i][4 + j]; s1 += a; s2 += a * a; }
#pragma unroll
        for (int off = 1; off < 16; off <<= 1) { s1 += __shfl_xor(s1, off); s2 += __shfl_xor(s2, off); }
        mean = s1 * (1.f / 64.f);
        var  = s2 * (1.f / 64.f) - mean * mean;
        rstd = rsqrtf(var + EPSLN);
        float kn[4];
#pragma unroll
        for (int j = 0; j < 4; ++j) {
            int c = tx + 16 * j;
            kn[j] = (acc[i][4 + j] - mean) * rstd * gk[c] + bk[c];
        }

        // ---- alpha / sigma dots (on normalized q) ----
        float da = 0.f, d0 = 0.f, d1 = 0.f;
#pragma unroll
        for (int j = 0; j < 4; ++j) {
            int c = tx + 16 * j;
            da += qn[j] * Wa[c];
            d0 += qn[j] * Wsig[2 * c];
            d1 += qn[j] * Wsig[2 * c + 1];
        }
#pragma unroll
        for (int off = 1; off < 16; off <<= 1) {
            da += __shfl_xor(da, off);
            d0 += __shfl_xor(d0, off);
            d1 += __shfl_xor(d1, off);
        }

        if (row < NROW) {
            size_t base = (size_t)row * 64;
#pragma unroll
            for (int j = 0; j < 4; ++j) {
                int c = tx + 16 * j;
                qo[base + c] = qn[j];
                ko[base + c] = kn[j];
                vo[base + c] = acc[i][8 + j];
            }
            if (tx == 0) {
                int b  = row / TDIM;
                int ti = row - b * TDIM;
                if (ti >= 1) {
                    int p = b * TPATCH + ti - 1;
                    float av = da + ba[0];
                    float sp = (av > 20.f) ? av : log1pf(__expf(av));
                    a8[p] = sp * (1.f / SCALE);
                    float sx = 1.f / (1.f + __expf(-(d0 + bsig[0])));
                    float sy = 1.f / (1.f + __expf(-(d1 + bsig[1])));
                    isx[p] = 0.5f / (sx * sx);
                    isy[p] = 0.5f / (sy * sy);
                }
            }
        }
    }
}

// ---------------------------------------------------------------------------
// Kernel 2: flash-style attention with Gaussian spatial bias.
// Block: (qtile, b). 32 queries, key tiles of 64. 256 threads.
// Score phase: thread(qg=t/16, lg=t%16) -> queries {2qg,2qg+1} x keys {4lg..4lg+3}
// PV phase:    thread(qg, lg)           -> queries {2qg,2qg+1} x dh   {4lg..4lg+3}
// m/l state lives consistently in each 16-lane qg group.
// ---------------------------------------------------------------------------
__global__ __launch_bounds__(256) void attn_kernel(
    const float* __restrict__ qi_, const float* __restrict__ ki_, const float* __restrict__ vi_,
    const float* __restrict__ a8, const float* __restrict__ isx, const float* __restrict__ isy,
    float* __restrict__ out)
{
    __shared__ float qT[64][34];   // qT[dh][q]
    __shared__ float kT[64][68];   // kT[dh][key]
    __shared__ float vs[64][68];   // vs[key][dh]
    __shared__ float pT[64][34];   // pT[key][q]

    const int t  = threadIdx.x;
    const int b  = blockIdx.y;
    const int q0 = blockIdx.x * 32;
    const int qg = t >> 4;
    const int lg = t & 15;

    // stage q tile transposed
#pragma unroll
    for (int it = 0; it < 2; ++it) {
        int idx = t + it * 256;          // 512 float4
        int ql  = idx >> 4;
        int d0  = (idx & 15) * 4;
        float4 v4 = make_float4(0.f, 0.f, 0.f, 0.f);
        int qglob = q0 + ql;
        if (qglob < TDIM) v4 = *(const float4*)&qi_[((size_t)b * TDIM + qglob) * 64 + d0];
        qT[d0 + 0][ql] = v4.x; qT[d0 + 1][ql] = v4.y;
        qT[d0 + 2][ql] = v4.z; qT[d0 + 3][ql] = v4.w;
    }

    // per-lane query metadata (2 queries)
    float a8q[2] = {0.f, 0.f}, isxq[2] = {0.f, 0.f}, isyq[2] = {0.f, 0.f};
    int   qpy[2] = {0, 0},     qpx[2] = {0, 0};
    bool  hasS[2] = {false, false};
#pragma unroll
    for (int qi2 = 0; qi2 < 2; ++qi2) {
        int qglob = q0 + qg * 2 + qi2;
        if (qglob >= 1 && qglob < TDIM) {
            int qp = qglob - 1;
            hasS[qi2] = true;
            a8q[qi2]  = a8 [b * TPATCH + qp];
            isxq[qi2] = isx[b * TPATCH + qp];
            isyq[qi2] = isy[b * TPATCH + qp];
            qpy[qi2] = qp >> 5; qpx[qi2] = qp & 31;
        }
    }

    float m[2] = {-1e30f, -1e30f}, l[2] = {0.f, 0.f};
    float oacc[2][4] = {{0.f,0.f,0.f,0.f},{0.f,0.f,0.f,0.f}};

    for (int kt0 = 0; kt0 < TDIM; kt0 += 64) {
        __syncthreads();   // previous PV done with vs/pT
        // stage k (transposed) and v tiles
#pragma unroll
        for (int it = 0; it < 4; ++it) {
            int idx = t + it * 256;      // 1024 float4
            int kl  = idx >> 4;
            int d0  = (idx & 15) * 4;
            int kglob = kt0 + kl;
            float4 kv4 = make_float4(0.f,0.f,0.f,0.f);
            float4 vv4 = make_float4(0.f,0.f,0.f,0.f);
            if (kglob < TDIM) {
                kv4 = *(const float4*)&ki_[((size_t)b * TDIM + kglob) * 64 + d0];
                vv4 = *(const float4*)&vi_[((size_t)b * TDIM + kglob) * 64 + d0];
            }
            kT[d0 + 0][kl] = kv4.x; kT[d0 + 1][kl] = kv4.y;
            kT[d0 + 2][kl] = kv4.z; kT[d0 + 3][kl] = kv4.w;
            *(float4*)&vs[kl][d0] = vv4;
        }
        __syncthreads();

        // ---- scores ----
        float s[2][4] = {{0.f,0.f,0.f,0.f},{0.f,0.f,0.f,0.f}};
#pragma unroll 16
        for (int dh = 0; dh < 64; ++dh) {
            float2 q2 = *(const float2*)&qT[dh][qg * 2];
            float4 k4 = *(const float4*)&kT[dh][lg * 4];
            s[0][0] += q2.x * k4.x; s[0][1] += q2.x * k4.y;
            s[0][2] += q2.x * k4.z; s[0][3] += q2.x * k4.w;
            s[1][0] += q2.y * k4.x; s[1][1] += q2.y * k4.y;
            s[1][2] += q2.y * k4.z; s[1][3] += q2.y * k4.w;
        }
#pragma unroll
        for (int qi2 = 0; qi2 < 2; ++qi2) {
#pragma unroll
            for (int kj = 0; kj < 4; ++kj) {
                int kglob = kt0 + lg * 4 + kj;
                float z = s[qi2][kj] * (1.f / SCALE);
                if (kglob >= 1 && kglob < TDIM && hasS[qi2]) {
                    int kp = kglob - 1;
                    float dy = (float)(qpy[qi2] - (kp >> 5));
                    float dx = (float)(qpx[qi2] - (kp & 31));
                    z += a8q[qi2] * __expf(-(dx * dx * isxq[qi2] + dy * dy * isyq[qi2]));
                }
                if (kglob >= TDIM) z = -1e30f;
                s[qi2][kj] = z;
            }
        }

        // ---- online softmax ----
        float tmax[2], tsum[2], sc[2];
#pragma unroll
        for (int qi2 = 0; qi2 < 2; ++qi2) {
            float mx = fmaxf(fmaxf(s[qi2][0], s[qi2][1]), fmaxf(s[qi2][2], s[qi2][3]));
#pragma unroll
            for (int off = 1; off < 16; off <<= 1) mx = fmaxf(mx, __shfl_xor(mx, off));
            tmax[qi2] = mx;
            float mn = fmaxf(m[qi2], mx);
            sc[qi2] = __expf(m[qi2] - mn);
            m[qi2]  = mn;
            float ts = 0.f;
#pragma unroll
            for (int kj = 0; kj < 4; ++kj) {
                float p = __expf(s[qi2][kj] - mn);
                s[qi2][kj] = p;
                ts += p;
            }
#pragma unroll
            for (int off = 1; off < 16; off <<= 1) ts += __shfl_xor(ts, off);
            tsum[qi2] = ts;
            l[qi2] = l[qi2] * sc[qi2] + ts;
        }

        // publish p
#pragma unroll
        for (int qi2 = 0; qi2 < 2; ++qi2)
#pragma unroll
            for (int kj = 0; kj < 4; ++kj)
                pT[lg * 4 + kj][qg * 2 + qi2] = s[qi2][kj];
        __syncthreads();

        // ---- PV ----
#pragma unroll
        for (int qi2 = 0; qi2 < 2; ++qi2)
#pragma unroll
            for (int mm = 0; mm < 4; ++mm) oacc[qi2][mm] *= sc[qi2];
#pragma unroll 16
        for (int key = 0; key < 64; ++key) {
            float2 p2 = *(const float2*)&pT[key][qg * 2];
            float4 v4 = *(const float4*)&vs[key][lg * 4];
            oacc[0][0] += p2.x * v4.x; oacc[0][1] += p2.x * v4.y;
            oacc[0][2] += p2.x * v4.z; oacc[0][3] += p2.x * v4.w;
            oacc[1][0] += p2.y * v4.x; oacc[1][1] += p2.y * v4.y;
            oacc[1][2] += p2.y * v4.z; oacc[1][3] += p2.y * v4.w;
        }
    }

    // ---- epilogue ----
#pragma unroll
    for (int qi2 = 0; qi2 < 2; ++qi2) {
        int qglob = q0 + qg * 2 + qi2;
        if (qglob < TDIM) {
            float rl = 1.f / l[qi2];
            float4 o4 = make_float4(oacc[qi2][0] * rl, oacc[qi2][1] * rl,
                                    oacc[qi2][2] * rl, oacc[qi2][3] * rl);
            *(float4*)&out[((size_t)b * TDIM + qglob) * 64 + lg * 4] = o4;
        }
    }
}

extern "C" void kernel_launch(void* const* d_in, const int* in_sizes, int n_in,
                              void* d_out, int out_size, void* d_ws, size_t ws_size,
                              hipStream_t stream)
{
    const float* x    = (const float*)d_in[0];
    const float* Wq   = (const float*)d_in[1];
    const float* Wk   = (const float*)d_in[2];
    const float* Wv   = (const float*)d_in[3];
    const float* gq   = (const float*)d_in[4];
    const float* bq   = (const float*)d_in[5];
    const float* gk   = (const float*)d_in[6];
    const float* bk   = (const float*)d_in[7];
    const float* Wsig = (const float*)d_in[8];
    const float* bsig = (const float*)d_in[9];
    const float* Wa   = (const float*)d_in[10];
    const float* ba   = (const float*)d_in[11];
    float* out = (float*)d_out;

    float* ws = (float*)d_ws;
    const size_t NQ = (size_t)BDIM * TDIM * 64;
    float* qo  = ws;
    float* ko  = qo + NQ;
    float* vo  = ko + NQ;
    float* a8  = vo + NQ;
    float* isx = a8 + (size_t)BDIM * TPATCH;
    float* isy = isx + (size_t)BDIM * TPATCH;

    const int nrow  = BDIM * TDIM;
    const int nblk1 = (nrow + 63) / 64;
    hipLaunchKernelGGL(qkv_kernel, dim3(nblk1), dim3(256), 0, stream,
                       x, Wq, Wk, Wv, gq, bq, gk, bk, Wsig, bsig, Wa, ba,
                       qo, ko, vo, a8, isx, isy);
    hipLaunchKernelGGL(attn_kernel, dim3(33, BDIM), dim3(256), 0, stream,
                       qo, ko, vo, a8, isx, isy, out);
}

// Round 2
// 353.320 us; speedup vs baseline: 1.9863x; 1.9863x over previous
//
#include <hip/hip_runtime.h>
#include <hip/hip_bf16.h>
#include <math.h>

#define BDIM 32
#define TDIM 1025
#define DDIM 768
#define GRIDW 32
#define TPATCH 1024
#define SCALE 8.0f
#define EPSLN 1e-5f
#define NROW (BDIM * TDIM)   // 32800

typedef __attribute__((ext_vector_type(8))) short short8v;   // 8 bf16 (4 VGPRs)
typedef __attribute__((ext_vector_type(4))) float f32x4;     // MFMA C/D frag

__device__ __forceinline__ unsigned short f2bf(float f) {
    unsigned int u = __float_as_uint(f);
    u += 0x7FFFu + ((u >> 16) & 1u);      // round-to-nearest-even
    return (unsigned short)(u >> 16);
}

// ---------------------------------------------------------------------------
// Kernel 0: W -> bf16, transposed: wT[c][k], c = 0..191 (q|k|v), k = 0..767
// ---------------------------------------------------------------------------
__global__ __launch_bounds__(256) void prep_w_kernel(
    const float* __restrict__ Wq, const float* __restrict__ Wk,
    const float* __restrict__ Wv, unsigned short* __restrict__ wT)
{
    const int c = blockIdx.x;                  // 0..191
    const float* W = (c < 64) ? Wq : (c < 128) ? Wk : Wv;
    const int cc = c & 63;
    for (int k = threadIdx.x; k < DDIM; k += 256)
        wT[(size_t)c * DDIM + k] = f2bf(W[(size_t)k * 64 + cc]);
}

// ---------------------------------------------------------------------------
// Kernel 1: MFMA QKV projection + fused LayerNorm(q,k) + alpha/sigma head.
// Block: 128 rows x 192 cols, 256 threads = 4 waves; wave w: rows 32w..32w+31,
// all 192 cols (Mf=2 x Nf=12 fragments of 16x16). K-loop: 24 steps of 32.
// ---------------------------------------------------------------------------
__global__ __launch_bounds__(256) void qkv_mfma_kernel(
    const float* __restrict__ x, const unsigned short* __restrict__ wT,
    const float* __restrict__ gq, const float* __restrict__ bq,
    const float* __restrict__ gk, const float* __restrict__ bk,
    const float* __restrict__ Wsig, const float* __restrict__ bsig,
    const float* __restrict__ Wa, const float* __restrict__ ba,
    float* __restrict__ qo, float* __restrict__ ko, float* __restrict__ vo,
    float* __restrict__ a8, float* __restrict__ isx, float* __restrict__ isy)
{
    __shared__ unsigned short As[128][40];   // rows x k, pad 40 (80B stride)
    __shared__ unsigned short Bs[192][40];   // cols x k, pad 40

    const int t  = threadIdx.x;
    const int wv = t >> 6;           // wave 0..3
    const int ln = t & 63;
    const int lq = ln >> 4;          // quarter-wave 0..3
    const int lr = ln & 15;
    const int r0 = blockIdx.x * 128;
    const int wrow = wv * 32;

    f32x4 acc[2][12];
#pragma unroll
    for (int mi = 0; mi < 2; ++mi)
#pragma unroll
        for (int ni = 0; ni < 12; ++ni)
            acc[mi][ni] = (f32x4){0.f, 0.f, 0.f, 0.f};

    for (int k0 = 0; k0 < DDIM; k0 += 32) {
        __syncthreads();
        // ---- stage A: 128 rows x 32 k, fp32 -> bf16 (1024 float4 slots) ----
#pragma unroll
        for (int it = 0; it < 4; ++it) {
            int lin = t + it * 256;
            int row = lin >> 3;
            int kk  = (lin & 7) * 4;
            int grow = r0 + row;
            float4 xv = make_float4(0.f, 0.f, 0.f, 0.f);
            if (grow < NROW) xv = *(const float4*)&x[(size_t)grow * DDIM + k0 + kk];
            ushort4 pk;
            pk.x = f2bf(xv.x); pk.y = f2bf(xv.y);
            pk.z = f2bf(xv.z); pk.w = f2bf(xv.w);
            *(ushort4*)&As[row][kk] = pk;
        }
        // ---- stage B: 192 cols x 32 k bf16 (1536 ushort4 slots) ----
#pragma unroll
        for (int it = 0; it < 6; ++it) {
            int lin = t + it * 256;
            int col = lin >> 3;
            int kk  = (lin & 7) * 4;
            *(ushort4*)&Bs[col][kk] =
                *(const ushort4*)&wT[(size_t)col * DDIM + k0 + kk];
        }
        __syncthreads();

        // ---- fragments + MFMA ----
        short8v a0 = *(const short8v*)&As[wrow +  0 + lr][lq * 8];
        short8v a1 = *(const short8v*)&As[wrow + 16 + lr][lq * 8];
#pragma unroll
        for (int ni = 0; ni < 12; ++ni) {
            short8v b = *(const short8v*)&Bs[16 * ni + lr][lq * 8];
            acc[0][ni] = __builtin_amdgcn_mfma_f32_16x16x32_bf16(a0, b, acc[0][ni], 0, 0, 0);
            acc[1][ni] = __builtin_amdgcn_mfma_f32_16x16x32_bf16(a1, b, acc[1][ni], 0, 0, 0);
        }
    }

    // ---- epilogue: LN(q), LN(k), alpha/sigma head, writes ----
    // per-thread col positions: c = lr + 16*ni
    float gqv[4], bqv[4], gkv[4], bkv[4], wav[4], ws0[4], ws1[4];
#pragma unroll
    for (int ni = 0; ni < 4; ++ni) {
        int c = lr + 16 * ni;
        gqv[ni] = gq[c]; bqv[ni] = bq[c];
        gkv[ni] = gk[c]; bkv[ni] = bk[c];
        wav[ni] = Wa[c];
        ws0[ni] = Wsig[2 * c];
        ws1[ni] = Wsig[2 * c + 1];
    }
    const float ba0 = ba[0], bs0 = bsig[0], bs1 = bsig[1];

#pragma unroll
    for (int mi = 0; mi < 2; ++mi) {
#pragma unroll
        for (int reg = 0; reg < 4; ++reg) {
            const int row = r0 + wrow + 16 * mi + lq * 4 + reg;

            // ---- q LN ----
            float s1 = 0.f, s2 = 0.f;
#pragma unroll
            for (int ni = 0; ni < 4; ++ni) {
                float v = acc[mi][ni][reg];
                s1 += v; s2 += v * v;
            }
#pragma unroll
            for (int off = 1; off < 16; off <<= 1) {
                s1 += __shfl_xor(s1, off);
                s2 += __shfl_xor(s2, off);
            }
            float mean = s1 * (1.f / 64.f);
            float var  = s2 * (1.f / 64.f) - mean * mean;
            float rstd = rsqrtf(var + EPSLN);
            float qn[4];
#pragma unroll
            for (int ni = 0; ni < 4; ++ni)
                qn[ni] = (acc[mi][ni][reg] - mean) * rstd * gqv[ni] + bqv[ni];

            // ---- k LN ----
            s1 = 0.f; s2 = 0.f;
#pragma unroll
            for (int ni = 0; ni < 4; ++ni) {
                float v = acc[mi][4 + ni][reg];
                s1 += v; s2 += v * v;
            }
#pragma unroll
            for (int off = 1; off < 16; off <<= 1) {
                s1 += __shfl_xor(s1, off);
                s2 += __shfl_xor(s2, off);
            }
            mean = s1 * (1.f / 64.f);
            var  = s2 * (1.f / 64.f) - mean * mean;
            rstd = rsqrtf(var + EPSLN);
            float kn[4];
#pragma unroll
            for (int ni = 0; ni < 4; ++ni)
                kn[ni] = (acc[mi][4 + ni][reg] - mean) * rstd * gkv[ni] + bkv[ni];

            // ---- head dots on normalized q ----
            float da = 0.f, d0 = 0.f, d1 = 0.f;
#pragma unroll
            for (int ni = 0; ni < 4; ++ni) {
                da += qn[ni] * wav[ni];
                d0 += qn[ni] * ws0[ni];
                d1 += qn[ni] * ws1[ni];
            }
#pragma unroll
            for (int off = 1; off < 16; off <<= 1) {
                da += __shfl_xor(da, off);
                d0 += __shfl_xor(d0, off);
                d1 += __shfl_xor(d1, off);
            }

            if (row < NROW) {
                size_t base = (size_t)row * 64;
#pragma unroll
                for (int ni = 0; ni < 4; ++ni) {
                    int c = lr + 16 * ni;
                    qo[base + c] = qn[ni];
                    ko[base + c] = kn[ni];
                    vo[base + c] = acc[mi][8 + ni][reg];
                }
                if (lr == 0) {
                    int b  = row / TDIM;
                    int ti = row - b * TDIM;
                    if (ti >= 1) {
                        int p = b * TPATCH + ti - 1;
                        float av = da + ba0;
                        float sp = (av > 20.f) ? av : log1pf(__expf(av));
                        a8[p] = sp * (1.f / SCALE);
                        float sx = 1.f / (1.f + __expf(-(d0 + bs0)));
                        float sy = 1.f / (1.f + __expf(-(d1 + bs1)));
                        isx[p] = 0.5f / (sx * sx);
                        isy[p] = 0.5f / (sy * sy);
                    }
                }
            }
        }
    }
}

// ---------------------------------------------------------------------------
// Kernel 2: flash-style attention with Gaussian spatial bias. (unchanged)
// ---------------------------------------------------------------------------
__global__ __launch_bounds__(256) void attn_kernel(
    const float* __restrict__ qi_, const float* __restrict__ ki_, const float* __restrict__ vi_,
    const float* __restrict__ a8, const float* __restrict__ isx, const float* __restrict__ isy,
    float* __restrict__ out)
{
    __shared__ float qT[64][34];   // qT[dh][q]
    __shared__ float kT[64][68];   // kT[dh][key]
    __shared__ float vs[64][68];   // vs[key][dh]
    __shared__ float pT[64][34];   // pT[key][q]

    const int t  = threadIdx.x;
    const int b  = blockIdx.y;
    const int q0 = blockIdx.x * 32;
    const int qg = t >> 4;
    const int lg = t & 15;

#pragma unroll
    for (int it = 0; it < 2; ++it) {
        int idx = t + it * 256;
        int ql  = idx >> 4;
        int d0  = (idx & 15) * 4;
        float4 v4 = make_float4(0.f, 0.f, 0.f, 0.f);
        int qglob = q0 + ql;
        if (qglob < TDIM) v4 = *(const float4*)&qi_[((size_t)b * TDIM + qglob) * 64 + d0];
        qT[d0 + 0][ql] = v4.x; qT[d0 + 1][ql] = v4.y;
        qT[d0 + 2][ql] = v4.z; qT[d0 + 3][ql] = v4.w;
    }

    float a8q[2] = {0.f, 0.f}, isxq[2] = {0.f, 0.f}, isyq[2] = {0.f, 0.f};
    int   qpy[2] = {0, 0},     qpx[2] = {0, 0};
    bool  hasS[2] = {false, false};
#pragma unroll
    for (int qi2 = 0; qi2 < 2; ++qi2) {
        int qglob = q0 + qg * 2 + qi2;
        if (qglob >= 1 && qglob < TDIM) {
            int qp = qglob - 1;
            hasS[qi2] = true;
            a8q[qi2]  = a8 [b * TPATCH + qp];
            isxq[qi2] = isx[b * TPATCH + qp];
            isyq[qi2] = isy[b * TPATCH + qp];
            qpy[qi2] = qp >> 5; qpx[qi2] = qp & 31;
        }
    }

    float m[2] = {-1e30f, -1e30f}, l[2] = {0.f, 0.f};
    float oacc[2][4] = {{0.f,0.f,0.f,0.f},{0.f,0.f,0.f,0.f}};

    for (int kt0 = 0; kt0 < TDIM; kt0 += 64) {
        __syncthreads();
#pragma unroll
        for (int it = 0; it < 4; ++it) {
            int idx = t + it * 256;
            int kl  = idx >> 4;
            int d0  = (idx & 15) * 4;
            int kglob = kt0 + kl;
            float4 kv4 = make_float4(0.f,0.f,0.f,0.f);
            float4 vv4 = make_float4(0.f,0.f,0.f,0.f);
            if (kglob < TDIM) {
                kv4 = *(const float4*)&ki_[((size_t)b * TDIM + kglob) * 64 + d0];
                vv4 = *(const float4*)&vi_[((size_t)b * TDIM + kglob) * 64 + d0];
            }
            kT[d0 + 0][kl] = kv4.x; kT[d0 + 1][kl] = kv4.y;
            kT[d0 + 2][kl] = kv4.z; kT[d0 + 3][kl] = kv4.w;
            *(float4*)&vs[kl][d0] = vv4;
        }
        __syncthreads();

        float s[2][4] = {{0.f,0.f,0.f,0.f},{0.f,0.f,0.f,0.f}};
#pragma unroll 16
        for (int dh = 0; dh < 64; ++dh) {
            float2 q2 = *(const float2*)&qT[dh][qg * 2];
            float4 k4 = *(const float4*)&kT[dh][lg * 4];
            s[0][0] += q2.x * k4.x; s[0][1] += q2.x * k4.y;
            s[0][2] += q2.x * k4.z; s[0][3] += q2.x * k4.w;
            s[1][0] += q2.y * k4.x; s[1][1] += q2.y * k4.y;
            s[1][2] += q2.y * k4.z; s[1][3] += q2.y * k4.w;
        }
#pragma unroll
        for (int qi2 = 0; qi2 < 2; ++qi2) {
#pragma unroll
            for (int kj = 0; kj < 4; ++kj) {
                int kglob = kt0 + lg * 4 + kj;
                float z = s[qi2][kj] * (1.f / SCALE);
                if (kglob >= 1 && kglob < TDIM && hasS[qi2]) {
                    int kp = kglob - 1;
                    float dy = (float)(qpy[qi2] - (kp >> 5));
                    float dx = (float)(qpx[qi2] - (kp & 31));
                    z += a8q[qi2] * __expf(-(dx * dx * isxq[qi2] + dy * dy * isyq[qi2]));
                }
                if (kglob >= TDIM) z = -1e30f;
                s[qi2][kj] = z;
            }
        }

        float sc[2];
#pragma unroll
        for (int qi2 = 0; qi2 < 2; ++qi2) {
            float mx = fmaxf(fmaxf(s[qi2][0], s[qi2][1]), fmaxf(s[qi2][2], s[qi2][3]));
#pragma unroll
            for (int off = 1; off < 16; off <<= 1) mx = fmaxf(mx, __shfl_xor(mx, off));
            float mn = fmaxf(m[qi2], mx);
            sc[qi2] = __expf(m[qi2] - mn);
            m[qi2]  = mn;
            float ts = 0.f;
#pragma unroll
            for (int kj = 0; kj < 4; ++kj) {
                float p = __expf(s[qi2][kj] - mn);
                s[qi2][kj] = p;
                ts += p;
            }
#pragma unroll
            for (int off = 1; off < 16; off <<= 1) ts += __shfl_xor(ts, off);
            l[qi2] = l[qi2] * sc[qi2] + ts;
        }

#pragma unroll
        for (int qi2 = 0; qi2 < 2; ++qi2)
#pragma unroll
            for (int kj = 0; kj < 4; ++kj)
                pT[lg * 4 + kj][qg * 2 + qi2] = s[qi2][kj];
        __syncthreads();

#pragma unroll
        for (int qi2 = 0; qi2 < 2; ++qi2)
#pragma unroll
            for (int mm = 0; mm < 4; ++mm) oacc[qi2][mm] *= sc[qi2];
#pragma unroll 16
        for (int key = 0; key < 64; ++key) {
            float2 p2 = *(const float2*)&pT[key][qg * 2];
            float4 v4 = *(const float4*)&vs[key][lg * 4];
            oacc[0][0] += p2.x * v4.x; oacc[0][1] += p2.x * v4.y;
            oacc[0][2] += p2.x * v4.z; oacc[0][3] += p2.x * v4.w;
            oacc[1][0] += p2.y * v4.x; oacc[1][1] += p2.y * v4.y;
            oacc[1][2] += p2.y * v4.z; oacc[1][3] += p2.y * v4.w;
        }
    }

#pragma unroll
    for (int qi2 = 0; qi2 < 2; ++qi2) {
        int qglob = q0 + qg * 2 + qi2;
        if (qglob < TDIM) {
            float rl = 1.f / l[qi2];
            float4 o4 = make_float4(oacc[qi2][0] * rl, oacc[qi2][1] * rl,
                                    oacc[qi2][2] * rl, oacc[qi2][3] * rl);
            *(float4*)&out[((size_t)b * TDIM + qglob) * 64 + lg * 4] = o4;
        }
    }
}

extern "C" void kernel_launch(void* const* d_in, const int* in_sizes, int n_in,
                              void* d_out, int out_size, void* d_ws, size_t ws_size,
                              hipStream_t stream)
{
    const float* x    = (const float*)d_in[0];
    const float* Wq   = (const float*)d_in[1];
    const float* Wk   = (const float*)d_in[2];
    const float* Wv   = (const float*)d_in[3];
    const float* gq   = (const float*)d_in[4];
    const float* bq   = (const float*)d_in[5];
    const float* gk   = (const float*)d_in[6];
    const float* bk   = (const float*)d_in[7];
    const float* Wsig = (const float*)d_in[8];
    const float* bsig = (const float*)d_in[9];
    const float* Wa   = (const float*)d_in[10];
    const float* ba   = (const float*)d_in[11];
    float* out = (float*)d_out;

    float* ws = (float*)d_ws;
    const size_t NQ = (size_t)NROW * 64;
    float* qo  = ws;
    float* ko  = qo + NQ;
    float* vo  = ko + NQ;
    float* a8  = vo + NQ;
    float* isx = a8 + (size_t)BDIM * TPATCH;
    float* isy = isx + (size_t)BDIM * TPATCH;
    unsigned short* wT = (unsigned short*)(isy + (size_t)BDIM * TPATCH);

    hipLaunchKernelGGL(prep_w_kernel, dim3(192), dim3(256), 0, stream,
                       Wq, Wk, Wv, wT);

    const int nblk1 = (NROW + 127) / 128;   // 257
    hipLaunchKernelGGL(qkv_mfma_kernel, dim3(nblk1), dim3(256), 0, stream,
                       x, wT, gq, bq, gk, bk, Wsig, bsig, Wa, ba,
                       qo, ko, vo, a8, isx, isy);

    hipLaunchKernelGGL(attn_kernel, dim3(33, BDIM), dim3(256), 0, stream,
                       qo, ko, vo, a8, isx, isy, out);
}

// Round 3
// 169.581 us; speedup vs baseline: 4.1384x; 2.0835x over previous
//
#include <hip/hip_runtime.h>
#include <hip/hip_bf16.h>
#include <math.h>

#define BDIM 32
#define TDIM 1025
#define DDIM 768
#define GRIDW 32
#define TPATCH 1024
#define SCALE 8.0f
#define EPSLN 1e-5f
#define NROW (BDIM * TDIM)   // 32800
#define VTLD 1088            // vT row stride (elements, 16B-aligned, >= 1024+64)
#define LDP  72              // LDS row stride (elements; 144B = 16B-aligned)

typedef __attribute__((ext_vector_type(8))) short short8v;   // 8 bf16 (4 VGPRs)
typedef __attribute__((ext_vector_type(4))) float f32x4;     // MFMA C/D frag

__device__ __forceinline__ unsigned short f2bf(float f) {
    unsigned int u = __float_as_uint(f);
    u += 0x7FFFu + ((u >> 16) & 1u);      // round-to-nearest-even
    return (unsigned short)(u >> 16);
}

// ---------------------------------------------------------------------------
// Kernel 0: W -> bf16, transposed: wT[c][k], c = 0..191 (q|k|v), k = 0..767
// ---------------------------------------------------------------------------
__global__ __launch_bounds__(256) void prep_w_kernel(
    const float* __restrict__ Wq, const float* __restrict__ Wk,
    const float* __restrict__ Wv, unsigned short* __restrict__ wT)
{
    const int c = blockIdx.x;                  // 0..191
    const float* W = (c < 64) ? Wq : (c < 128) ? Wk : Wv;
    const int cc = c & 63;
    for (int k = threadIdx.x; k < DDIM; k += 256)
        wT[(size_t)c * DDIM + k] = f2bf(W[(size_t)k * 64 + cc]);
}

// ---------------------------------------------------------------------------
// Kernel 1: MFMA QKV projection + fused LayerNorm(q,k) + alpha/sigma head.
// Outputs: qb, kb bf16 [row][64]; vT bf16 [b][dh][token] (pre-transposed).
// ---------------------------------------------------------------------------
__global__ __launch_bounds__(256) void qkv_mfma_kernel(
    const float* __restrict__ x, const unsigned short* __restrict__ wT,
    const float* __restrict__ gq, const float* __restrict__ bq,
    const float* __restrict__ gk, const float* __restrict__ bk,
    const float* __restrict__ Wsig, const float* __restrict__ bsig,
    const float* __restrict__ Wa, const float* __restrict__ ba,
    unsigned short* __restrict__ qb, unsigned short* __restrict__ kb,
    unsigned short* __restrict__ vT,
    float* __restrict__ a8, float* __restrict__ isx, float* __restrict__ isy)
{
    __shared__ unsigned short As[128][40];   // rows x k, pad 40 (80B stride)
    __shared__ unsigned short Bs[192][40];   // cols x k, pad 40

    const int t  = threadIdx.x;
    const int wv = t >> 6;           // wave 0..3
    const int ln = t & 63;
    const int lq = ln >> 4;          // quarter-wave 0..3
    const int lr = ln & 15;
    const int r0 = blockIdx.x * 128;
    const int wrow = wv * 32;

    f32x4 acc[2][12];
#pragma unroll
    for (int mi = 0; mi < 2; ++mi)
#pragma unroll
        for (int ni = 0; ni < 12; ++ni)
            acc[mi][ni] = (f32x4){0.f, 0.f, 0.f, 0.f};

    for (int k0 = 0; k0 < DDIM; k0 += 32) {
        __syncthreads();
        // ---- stage A: 128 rows x 32 k, fp32 -> bf16 ----
#pragma unroll
        for (int it = 0; it < 4; ++it) {
            int lin = t + it * 256;
            int row = lin >> 3;
            int kk  = (lin & 7) * 4;
            int grow = r0 + row;
            float4 xv = make_float4(0.f, 0.f, 0.f, 0.f);
            if (grow < NROW) xv = *(const float4*)&x[(size_t)grow * DDIM + k0 + kk];
            ushort4 pk;
            pk.x = f2bf(xv.x); pk.y = f2bf(xv.y);
            pk.z = f2bf(xv.z); pk.w = f2bf(xv.w);
            *(ushort4*)&As[row][kk] = pk;
        }
        // ---- stage B: 192 cols x 32 k bf16 ----
#pragma unroll
        for (int it = 0; it < 6; ++it) {
            int lin = t + it * 256;
            int col = lin >> 3;
            int kk  = (lin & 7) * 4;
            *(ushort4*)&Bs[col][kk] =
                *(const ushort4*)&wT[(size_t)col * DDIM + k0 + kk];
        }
        __syncthreads();

        short8v a0 = *(const short8v*)&As[wrow +  0 + lr][lq * 8];
        short8v a1 = *(const short8v*)&As[wrow + 16 + lr][lq * 8];
#pragma unroll
        for (int ni = 0; ni < 12; ++ni) {
            short8v b = *(const short8v*)&Bs[16 * ni + lr][lq * 8];
            acc[0][ni] = __builtin_amdgcn_mfma_f32_16x16x32_bf16(a0, b, acc[0][ni], 0, 0, 0);
            acc[1][ni] = __builtin_amdgcn_mfma_f32_16x16x32_bf16(a1, b, acc[1][ni], 0, 0, 0);
        }
    }

    // ---- epilogue: LN(q), LN(k), alpha/sigma head, writes ----
    float gqv[4], bqv[4], gkv[4], bkv[4], wav[4], ws0[4], ws1[4];
#pragma unroll
    for (int ni = 0; ni < 4; ++ni) {
        int c = lr + 16 * ni;
        gqv[ni] = gq[c]; bqv[ni] = bq[c];
        gkv[ni] = gk[c]; bkv[ni] = bk[c];
        wav[ni] = Wa[c];
        ws0[ni] = Wsig[2 * c];
        ws1[ni] = Wsig[2 * c + 1];
    }
    const float ba0 = ba[0], bs0 = bsig[0], bs1 = bsig[1];

#pragma unroll
    for (int mi = 0; mi < 2; ++mi) {
#pragma unroll
        for (int reg = 0; reg < 4; ++reg) {
            const int row = r0 + wrow + 16 * mi + lq * 4 + reg;

            // ---- q LN ----
            float s1 = 0.f, s2 = 0.f;
#pragma unroll
            for (int ni = 0; ni < 4; ++ni) {
                float v = acc[mi][ni][reg];
                s1 += v; s2 += v * v;
            }
#pragma unroll
            for (int off = 1; off < 16; off <<= 1) {
                s1 += __shfl_xor(s1, off);
                s2 += __shfl_xor(s2, off);
            }
            float mean = s1 * (1.f / 64.f);
            float var  = s2 * (1.f / 64.f) - mean * mean;
            float rstd = rsqrtf(var + EPSLN);
            float qn[4];
#pragma unroll
            for (int ni = 0; ni < 4; ++ni)
                qn[ni] = (acc[mi][ni][reg] - mean) * rstd * gqv[ni] + bqv[ni];

            // ---- k LN ----
            s1 = 0.f; s2 = 0.f;
#pragma unroll
            for (int ni = 0; ni < 4; ++ni) {
                float v = acc[mi][4 + ni][reg];
                s1 += v; s2 += v * v;
            }
#pragma unroll
            for (int off = 1; off < 16; off <<= 1) {
                s1 += __shfl_xor(s1, off);
                s2 += __shfl_xor(s2, off);
            }
            mean = s1 * (1.f / 64.f);
            var  = s2 * (1.f / 64.f) - mean * mean;
            rstd = rsqrtf(var + EPSLN);
            float kn[4];
#pragma unroll
            for (int ni = 0; ni < 4; ++ni)
                kn[ni] = (acc[mi][4 + ni][reg] - mean) * rstd * gkv[ni] + bkv[ni];

            // ---- head dots on normalized q ----
            float da = 0.f, d0 = 0.f, d1 = 0.f;
#pragma unroll
            for (int ni = 0; ni < 4; ++ni) {
                da += qn[ni] * wav[ni];
                d0 += qn[ni] * ws0[ni];
                d1 += qn[ni] * ws1[ni];
            }
#pragma unroll
            for (int off = 1; off < 16; off <<= 1) {
                da += __shfl_xor(da, off);
                d0 += __shfl_xor(d0, off);
                d1 += __shfl_xor(d1, off);
            }

            if (row < NROW) {
                size_t base = (size_t)row * 64;
                int bidx = row / TDIM;
                int ti   = row - bidx * TDIM;
#pragma unroll
                for (int ni = 0; ni < 4; ++ni) {
                    int c = lr + 16 * ni;
                    qb[base + c] = f2bf(qn[ni]);
                    kb[base + c] = f2bf(kn[ni]);
                    vT[((size_t)bidx * 64 + c) * VTLD + ti] = f2bf(acc[mi][8 + ni][reg]);
                }
                if (lr == 0 && ti >= 1) {
                    int p = bidx * TPATCH + ti - 1;
                    float av = da + ba0;
                    float sp = (av > 20.f) ? av : log1pf(__expf(av));
                    a8[p] = sp * (1.f / SCALE);
                    float sx = 1.f / (1.f + __expf(-(d0 + bs0)));
                    float sy = 1.f / (1.f + __expf(-(d1 + bs1)));
                    isx[p] = 0.5f / (sx * sx);
                    isy[p] = 0.5f / (sy * sy);
                }
            }
        }
    }
}

// ---------------------------------------------------------------------------
// Kernel 2: MFMA flash attention with Gaussian spatial bias.
// Block: (qtile 64, b), 4 waves; wave = 16 queries. K-tiles of 64.
// Score C-frag: row=(lq*4+reg)=query-in-16, col=lr=key-in-16 (frag ni).
// ---------------------------------------------------------------------------
__global__ __launch_bounds__(256) void attn_mfma_kernel(
    const unsigned short* __restrict__ qb, const unsigned short* __restrict__ kb,
    const unsigned short* __restrict__ vT,
    const float* __restrict__ a8, const float* __restrict__ isx,
    const float* __restrict__ isy, float* __restrict__ out)
{
    __shared__ unsigned short Qs[64][LDP];
    __shared__ unsigned short Ks[64][LDP];
    __shared__ unsigned short Vt[64][LDP];      // [dh][key]
    __shared__ unsigned short Pt[4][16][LDP];   // per-wave [q][key]

    const int t  = threadIdx.x;
    const int wv = t >> 6;
    const int ln = t & 63;
    const int lq = ln >> 4;
    const int lr = ln & 15;
    const int bb = blockIdx.y;
    const int q0 = blockIdx.x * 64;

    // ---- stage Q (64 x 64 bf16) ----
#pragma unroll
    for (int it = 0; it < 2; ++it) {
        int lin = t + it * 256;
        int row = lin >> 3;
        int d0  = (lin & 7) * 8;
        short8v v8 = {0,0,0,0,0,0,0,0};
        int qg = q0 + row;
        if (qg < TDIM) v8 = *(const short8v*)&qb[((size_t)bb * TDIM + qg) * 64 + d0];
        *(short8v*)&Qs[row][d0] = v8;
    }
    __syncthreads();

    const short8v aq0 = *(const short8v*)&Qs[wv * 16 + lr][lq * 8];
    const short8v aq1 = *(const short8v*)&Qs[wv * 16 + lr][32 + lq * 8];

    // ---- per-reg query metadata (queries q0 + wv*16 + lq*4 + reg) ----
    float a8q[4], sxq[4], syq[4], qpy[4], qpx[4];
    bool  hasS[4];
#pragma unroll
    for (int reg = 0; reg < 4; ++reg) {
        int qg = q0 + wv * 16 + lq * 4 + reg;
        hasS[reg] = false;
        a8q[reg] = 0.f; sxq[reg] = 0.f; syq[reg] = 0.f; qpy[reg] = 0.f; qpx[reg] = 0.f;
        if (qg >= 1 && qg < TDIM) {
            int qp = qg - 1;
            hasS[reg] = true;
            a8q[reg] = a8 [bb * TPATCH + qp];
            sxq[reg] = isx[bb * TPATCH + qp];
            syq[reg] = isy[bb * TPATCH + qp];
            qpy[reg] = (float)(qp >> 5);
            qpx[reg] = (float)(qp & 31);
        }
    }

    float m[4]  = {-1e30f, -1e30f, -1e30f, -1e30f};
    float l[4]  = {0.f, 0.f, 0.f, 0.f};
    f32x4 oacc[4];
#pragma unroll
    for (int ni = 0; ni < 4; ++ni) oacc[ni] = (f32x4){0.f, 0.f, 0.f, 0.f};

    for (int kt0 = 0; kt0 < TDIM; kt0 += 64) {
        __syncthreads();
        // ---- stage K tile (row-major) ----
#pragma unroll
        for (int it = 0; it < 2; ++it) {
            int lin = t + it * 256;
            int key = lin >> 3;
            int d0  = (lin & 7) * 8;
            short8v v8 = {0,0,0,0,0,0,0,0};
            int kg = kt0 + key;
            if (kg < TDIM) v8 = *(const short8v*)&kb[((size_t)bb * TDIM + kg) * 64 + d0];
            *(short8v*)&Ks[key][d0] = v8;
        }
        // ---- stage V tile from pre-transposed vT: linear, conflict-free ----
#pragma unroll
        for (int it = 0; it < 2; ++it) {
            int lin = t + it * 256;
            int dh = lin >> 3;
            int k0 = (lin & 7) * 8;
            short8v v8 = *(const short8v*)&vT[((size_t)bb * 64 + dh) * VTLD + kt0 + k0];
            *(short8v*)&Vt[dh][k0] = v8;
        }
        __syncthreads();

        // ---- scores: S = Q K^T ----
        f32x4 sac[4];
#pragma unroll
        for (int ni = 0; ni < 4; ++ni) sac[ni] = (f32x4){0.f, 0.f, 0.f, 0.f};
#pragma unroll
        for (int ni = 0; ni < 4; ++ni) {
            short8v b0 = *(const short8v*)&Ks[16 * ni + lr][lq * 8];
            short8v b1 = *(const short8v*)&Ks[16 * ni + lr][32 + lq * 8];
            sac[ni] = __builtin_amdgcn_mfma_f32_16x16x32_bf16(aq0, b0, sac[ni], 0, 0, 0);
            sac[ni] = __builtin_amdgcn_mfma_f32_16x16x32_bf16(aq1, b1, sac[ni], 0, 0, 0);
        }

        // ---- bias + mask ----
#pragma unroll
        for (int ni = 0; ni < 4; ++ni) {
            int key = kt0 + 16 * ni + lr;
            int kp  = key - 1;
            float ky = (float)(kp >> 5);
            float kx = (float)(kp & 31);
            bool kvalid = (key >= 1) && (key < TDIM);
#pragma unroll
            for (int reg = 0; reg < 4; ++reg) {
                float z = sac[ni][reg] * (1.f / SCALE);
                if (kvalid && hasS[reg]) {
                    float dy = qpy[reg] - ky;
                    float dx = qpx[reg] - kx;
                    z += a8q[reg] * __expf(-(dx * dx * sxq[reg] + dy * dy * syq[reg]));
                }
                if (key >= TDIM) z = -1e30f;
                sac[ni][reg] = z;
            }
        }

        // ---- online softmax (per query row = per reg) ----
        float scf[4];
#pragma unroll
        for (int reg = 0; reg < 4; ++reg) {
            float mx = fmaxf(fmaxf(sac[0][reg], sac[1][reg]),
                             fmaxf(sac[2][reg], sac[3][reg]));
#pragma unroll
            for (int off = 1; off < 16; off <<= 1) mx = fmaxf(mx, __shfl_xor(mx, off));
            float mn = fmaxf(m[reg], mx);
            scf[reg] = __expf(m[reg] - mn);
            m[reg] = mn;
            float ts = 0.f;
#pragma unroll
            for (int ni = 0; ni < 4; ++ni) {
                float pp = __expf(sac[ni][reg] - mn);
                sac[ni][reg] = pp;
                ts += pp;
            }
#pragma unroll
            for (int off = 1; off < 16; off <<= 1) ts += __shfl_xor(ts, off);
            l[reg] = l[reg] * scf[reg] + ts;
        }
#pragma unroll
        for (int ni = 0; ni < 4; ++ni)
#pragma unroll
            for (int reg = 0; reg < 4; ++reg)
                oacc[ni][reg] *= scf[reg];

        // ---- publish P (wave-private tile, no barrier needed) ----
#pragma unroll
        for (int ni = 0; ni < 4; ++ni)
#pragma unroll
            for (int reg = 0; reg < 4; ++reg)
                Pt[wv][lq * 4 + reg][16 * ni + lr] = f2bf(sac[ni][reg]);

        // ---- PV: O += P V ----
#pragma unroll
        for (int ks = 0; ks < 2; ++ks) {
            short8v pa = *(const short8v*)&Pt[wv][lr][ks * 32 + lq * 8];
#pragma unroll
            for (int ni = 0; ni < 4; ++ni) {
                short8v bv = *(const short8v*)&Vt[16 * ni + lr][ks * 32 + lq * 8];
                oacc[ni] = __builtin_amdgcn_mfma_f32_16x16x32_bf16(pa, bv, oacc[ni], 0, 0, 0);
            }
        }
    }

    // ---- epilogue ----
#pragma unroll
    for (int reg = 0; reg < 4; ++reg) {
        int qg = q0 + wv * 16 + lq * 4 + reg;
        if (qg < TDIM) {
            float rl = 1.f / l[reg];
#pragma unroll
            for (int ni = 0; ni < 4; ++ni)
                out[((size_t)bb * TDIM + qg) * 64 + 16 * ni + lr] = oacc[ni][reg] * rl;
        }
    }
}

extern "C" void kernel_launch(void* const* d_in, const int* in_sizes, int n_in,
                              void* d_out, int out_size, void* d_ws, size_t ws_size,
                              hipStream_t stream)
{
    const float* x    = (const float*)d_in[0];
    const float* Wq   = (const float*)d_in[1];
    const float* Wk   = (const float*)d_in[2];
    const float* Wv   = (const float*)d_in[3];
    const float* gq   = (const float*)d_in[4];
    const float* bq   = (const float*)d_in[5];
    const float* gk   = (const float*)d_in[6];
    const float* bk   = (const float*)d_in[7];
    const float* Wsig = (const float*)d_in[8];
    const float* bsig = (const float*)d_in[9];
    const float* Wa   = (const float*)d_in[10];
    const float* ba   = (const float*)d_in[11];
    float* out = (float*)d_out;

    // ---- workspace layout (bytes) ----
    char* w = (char*)d_ws;
    const size_t NQ = (size_t)NROW * 64;                 // q/k elems
    unsigned short* qb = (unsigned short*)w;              w += NQ * 2;
    unsigned short* kb = (unsigned short*)w;              w += NQ * 2;
    unsigned short* vT = (unsigned short*)w;              w += (size_t)BDIM * 64 * VTLD * 2;
    float* a8  = (float*)w;                               w += (size_t)BDIM * TPATCH * 4;
    float* isx = (float*)w;                               w += (size_t)BDIM * TPATCH * 4;
    float* isy = (float*)w;                               w += (size_t)BDIM * TPATCH * 4;
    unsigned short* wT = (unsigned short*)w;              w += (size_t)192 * DDIM * 2;

    // zero vT (covers the padded tail so OOB key loads read finite zeros)
    hipMemsetAsync(vT, 0, (size_t)BDIM * 64 * VTLD * 2, stream);

    hipLaunchKernelGGL(prep_w_kernel, dim3(192), dim3(256), 0, stream,
                       Wq, Wk, Wv, wT);

    const int nblk1 = (NROW + 127) / 128;   // 257
    hipLaunchKernelGGL(qkv_mfma_kernel, dim3(nblk1), dim3(256), 0, stream,
                       x, wT, gq, bq, gk, bk, Wsig, bsig, Wa, ba,
                       qb, kb, vT, a8, isx, isy);

    hipLaunchKernelGGL(attn_mfma_kernel, dim3(17, BDIM), dim3(256), 0, stream,
                       qb, kb, vT, a8, isx, isy, out);
}